// Round 9
// baseline (1058.464 us; speedup 1.0000x reference)
//
#include <hip/hip_runtime.h>
#include <hip/hip_fp16.h>

#define NN 100000
#define EE 1600000
#define SCAN_CHUNK 1024
#define NBLK ((NN + SCAN_CHUNK - 1) / SCAN_CHUNK)  // 98
#define RB 64                       // range-scatter blocks
#define RNG ((NN + RB - 1) / RB)    // 1563 dst nodes per range

// ---------- GEMM (Nx128)@(128x128), fp16 out + fused el/er; INHALF: fp16 in ----------
template <int INHALF>
__global__ __launch_bounds__(256) void gemm_el_k(const void* __restrict__ Xv,
                                                 const float* __restrict__ W,
                                                 const float* __restrict__ al,
                                                 const float* __restrict__ ar,
                                                 __half* __restrict__ Hout,
                                                 float* __restrict__ el,
                                                 float* __restrict__ er) {
    __shared__ float Xs[32 * 128];
    __shared__ float Ws[32 * 128];
    int t = threadIdx.x;
    int row0 = blockIdx.x * 32;

    float4* Xs4 = (float4*)Xs;
    if (INHALF) {
        const uint2* Xh = (const uint2*)((const __half*)Xv + (size_t)row0 * 128);
#pragma unroll
        for (int i = 0; i < 4; i++) {
            uint2 u = Xh[i * 256 + t];
            float2 fa = __half22float2(__builtin_bit_cast(__half2, u.x));
            float2 fb = __half22float2(__builtin_bit_cast(__half2, u.y));
            Xs4[i * 256 + t] = make_float4(fa.x, fa.y, fb.x, fb.y);
        }
    } else {
        const float4* X4 = (const float4*)((const float*)Xv + (size_t)row0 * 128);
#pragma unroll
        for (int i = 0; i < 4; i++) Xs4[i * 256 + t] = X4[i * 256 + t];
    }

    int tr = t >> 5, tc = t & 31;
    float acc[4][4] = {};
    for (int kb = 0; kb < 4; kb++) {
        const float4* W4 = (const float4*)(W + kb * 32 * 128);
        float4* Ws4 = (float4*)Ws;
        __syncthreads();
#pragma unroll
        for (int i = 0; i < 4; i++) Ws4[i * 256 + t] = W4[i * 256 + t];
        __syncthreads();
#pragma unroll
        for (int k = 0; k < 32; k += 2) {
            float2 xr[4];
#pragma unroll
            for (int i = 0; i < 4; i++)
                xr[i] = *(const float2*)&Xs[(tr * 4 + i) * 128 + kb * 32 + k];
            float4 w0 = *(const float4*)&Ws[k * 128 + tc * 4];
            float4 w1 = *(const float4*)&Ws[(k + 1) * 128 + tc * 4];
#pragma unroll
            for (int i = 0; i < 4; i++) {
                acc[i][0] += xr[i].x * w0.x + xr[i].y * w1.x;
                acc[i][1] += xr[i].x * w0.y + xr[i].y * w1.y;
                acc[i][2] += xr[i].x * w0.z + xr[i].y * w1.z;
                acc[i][3] += xr[i].x * w0.w + xr[i].y * w1.w;
            }
        }
    }
#pragma unroll
    for (int i = 0; i < 4; i++) {
        __half2 p0 = __floats2half2_rn(acc[i][0], acc[i][1]);
        __half2 p1 = __floats2half2_rn(acc[i][2], acc[i][3]);
        __half2* dstp = (__half2*)&Hout[(size_t)(row0 + tr * 4 + i) * 128 + tc * 4];
        dstp[0] = p0;
        dstp[1] = p1;
    }
    int hd = tc >> 3;
    float4 a_l = *(const float4*)&al[hd * 32 + (tc & 7) * 4];
    float4 a_r = *(const float4*)&ar[hd * 32 + (tc & 7) * 4];
#pragma unroll
    for (int i = 0; i < 4; i++) {
        float pl = acc[i][0] * a_l.x + acc[i][1] * a_l.y + acc[i][2] * a_l.z + acc[i][3] * a_l.w;
        float pr = acc[i][0] * a_r.x + acc[i][1] * a_r.y + acc[i][2] * a_r.z + acc[i][3] * a_r.w;
#pragma unroll
        for (int off = 1; off < 8; off <<= 1) {
            pl += __shfl_xor(pl, off, 64);
            pr += __shfl_xor(pr, off, 64);
        }
        if ((t & 7) == 0) {
            int r = row0 + tr * 4 + i;
            el[r * 4 + hd] = pl;
            er[r * 4 + hd] = pr;
        }
    }
}

// ---------------- CSR build (once per call) ----------------
__global__ void degcount_k(const int* __restrict__ dst, int* __restrict__ deg) {
    int e = blockIdx.x * blockDim.x + threadIdx.x;
    if (e < EE) atomicAdd(&deg[dst[e]], 1);
}

__global__ __launch_bounds__(256) void blocksum_k(const int* __restrict__ deg,
                                                  int* __restrict__ bsum) {
    int b = blockIdx.x, t = threadIdx.x;
    int base = b * SCAN_CHUNK + t * 4;
    int s = 0;
    if (base + 3 < NN) {
        int4 v = *(const int4*)&deg[base];
        s = v.x + v.y + v.z + v.w;
    } else {
        for (int i = base; i < NN; ++i) s += deg[i];
    }
#pragma unroll
    for (int off = 1; off < 64; off <<= 1) s += __shfl_xor(s, off, 64);
    __shared__ int wsum[4];
    if ((t & 63) == 0) wsum[t >> 6] = s;
    __syncthreads();
    if (t == 0) bsum[b] = wsum[0] + wsum[1] + wsum[2] + wsum[3];
}

__global__ __launch_bounds__(128) void bscan_k(const int* __restrict__ bsum,
                                               int* __restrict__ boff,
                                               int* __restrict__ rowptr) {
    __shared__ int sh[128];
    int t = threadIdx.x;
    int v = (t < NBLK) ? bsum[t] : 0;
    sh[t] = v;
    __syncthreads();
    for (int off = 1; off < 128; off <<= 1) {
        int u = (t >= off) ? sh[t - off] : 0;
        __syncthreads();
        sh[t] += u;
        __syncthreads();
    }
    if (t < NBLK) boff[t] = sh[t] - v;
    if (t == 0) rowptr[NN] = EE;
}

__global__ __launch_bounds__(256) void scanout_k(const int* __restrict__ deg,
                                                 const int* __restrict__ boff,
                                                 int* __restrict__ rowptr) {
    int b = blockIdx.x, t = threadIdx.x;
    int base = b * SCAN_CHUNK + t * 4;
    int v0 = 0, v1 = 0, v2 = 0, v3 = 0;
    if (base + 3 < NN) {
        int4 v = *(const int4*)&deg[base];
        v0 = v.x; v1 = v.y; v2 = v.z; v3 = v.w;
    } else if (base < NN) {
        v0 = deg[base];
        if (base + 1 < NN) v1 = deg[base + 1];
        if (base + 2 < NN) v2 = deg[base + 2];
    }
    int tot = v0 + v1 + v2 + v3;
    __shared__ int sh[256];
    sh[t] = tot;
    __syncthreads();
    for (int off = 1; off < 256; off <<= 1) {
        int u = (t >= off) ? sh[t - off] : 0;
        __syncthreads();
        sh[t] += u;
        __syncthreads();
    }
    int ex = sh[t] - tot + boff[b];
    if (base + 3 < NN) {
        int4 rv = make_int4(ex, ex + v0, ex + v0 + v1, ex + v0 + v1 + v2);
        *(int4*)&rowptr[base] = rv;
    } else if (base < NN) {
        rowptr[base] = ex;
        if (base + 1 < NN) rowptr[base + 1] = ex + v0;
        if (base + 2 < NN) rowptr[base + 2] = ex + v0 + v1;
    }
}

// XCD-local range scatter: each block owns dst range [lo, lo+RNG), cursors in
// LDS, so all csr_src writes for a 100 KB region come from ONE CU/XCD and the
// region stays L2-resident -> evicts once instead of per-store write-through.
__global__ __launch_bounds__(512) void scatter_rng_k(const int* __restrict__ src,
                                                     const int* __restrict__ dst,
                                                     const int* __restrict__ rowptr,
                                                     int* __restrict__ csr_src) {
    __shared__ int cur[RNG];
    int lo = blockIdx.x * RNG;
    int hi = lo + RNG; if (hi > NN) hi = NN;
    int nr = hi - lo;
    for (int i = threadIdx.x; i < nr; i += 512) cur[i] = rowptr[lo + i];
    __syncthreads();
    for (int e0 = threadIdx.x * 4; e0 < EE; e0 += 512 * 4) {
        int4 d4 = *(const int4*)&dst[e0];
        int dd[4] = {d4.x, d4.y, d4.z, d4.w};
#pragma unroll
        for (int j = 0; j < 4; ++j) {
            unsigned r = (unsigned)(dd[j] - lo);
            if (r < (unsigned)nr) {
                int p = atomicAdd(&cur[r], 1);
                csr_src[p] = src[e0 + j];
            }
        }
    }
}

// ---------- fused per-node softmax + aggregation (no-max, masked-32 chunks) ----------
template <int FINAL>
__global__ __launch_bounds__(256) void gat_agg_k(const int* __restrict__ rowptr,
                                                 const int* __restrict__ csr_src,
                                                 const float* __restrict__ el,
                                                 const float* __restrict__ er,
                                                 const __half* __restrict__ h,
                                                 const float* __restrict__ bias,
                                                 void* __restrict__ outv,
                                                 const float* __restrict__ Wf,
                                                 const float* __restrict__ bf) {
    int wave = (blockIdx.x * 256 + threadIdx.x) >> 6;
    if (wave >= NN) return;
    int lane = threadIdx.x & 63;
    int row = rowptr[wave], end = rowptr[wave + 1];
    int hd = lane >> 4, sub = lane & 15;
    float erd = er[wave * 4 + hd];

    float dpart = 0.f, acc0 = 0.f, acc1 = 0.f;
    for (int base = row; base < end; base += 32) {
        int c = end - base;
        int s0 = csr_src[base + (sub < c ? sub : 0)];
        int s1 = csr_src[base + (16 + sub < c ? 16 + sub : 0)];
        __half2 hv[32];
#pragma unroll
        for (int i = 0; i < 16; ++i) {
            int si = __builtin_amdgcn_readlane(s0, i);
            hv[i] = *(const __half2*)(h + (size_t)si * 128 + lane * 2);
        }
#pragma unroll
        for (int i = 0; i < 16; ++i) {
            int si = __builtin_amdgcn_readlane(s1, i);
            hv[16 + i] = *(const __half2*)(h + (size_t)si * 128 + lane * 2);
        }
        float a0 = 0.f, a1 = 0.f;
        if (sub < c) {
            float v = el[s0 * 4 + hd] + erd;
            v = (v >= 0.f) ? v : 0.2f * v;
            a0 = __expf(v);
        }
        if (16 + sub < c) {
            float v = el[s1 * 4 + hd] + erd;
            v = (v >= 0.f) ? v : 0.2f * v;
            a1 = __expf(v);
        }
        dpart += a0 + a1;
#pragma unroll
        for (int i = 0; i < 16; ++i) {
            float ai = __shfl(a0, (hd << 4) | i, 64);
            float2 f = __half22float2(hv[i]);
            acc0 = fmaf(ai, f.x, acc0);
            acc1 = fmaf(ai, f.y, acc1);
        }
#pragma unroll
        for (int i = 0; i < 16; ++i) {
            float ai = __shfl(a1, (hd << 4) | i, 64);
            float2 f = __half22float2(hv[16 + i]);
            acc0 = fmaf(ai, f.x, acc0);
            acc1 = fmaf(ai, f.y, acc1);
        }
    }
    float denom = dpart;
#pragma unroll
    for (int off = 1; off < 16; off <<= 1) denom += __shfl_xor(denom, off, 64);
    float inv = 1.f / fmaxf(denom, 1e-9f);
    float2 bv = *(const float2*)&bias[lane * 2];
    float o0 = acc0 * inv + bv.x;
    float o1 = acc1 * inv + bv.y;

    if (FINAL) {
        float* out = (float*)outv;
        float4 wf = *(const float4*)&Wf[lane * 4];
        float c0 = o0 * wf.x + o1 * wf.z;
        float c1 = o0 * wf.y + o1 * wf.w;
#pragma unroll
        for (int off = 1; off < 64; off <<= 1) {
            c0 += __shfl_xor(c0, off, 64);
            c1 += __shfl_xor(c1, off, 64);
        }
        if (lane == 0) {
            float2 res = make_float2(c0 + bf[0], c1 + bf[1]);
            *(float2*)&out[(size_t)wave * 2] = res;
        }
    } else {
        __half* out = (__half*)outv;
        *(__half2*)&out[(size_t)wave * 128 + lane * 2] = __floats2half2_rn(o0, o1);
    }
}

extern "C" void kernel_launch(void* const* d_in, const int* in_sizes, int n_in,
                              void* d_out, int out_size, void* d_ws, size_t ws_size,
                              hipStream_t stream) {
    const float* x   = (const float*)d_in[0];
    const int*   src = (const int*)d_in[1];
    const int*   dst = (const int*)d_in[2];
    const float* W1  = (const float*)d_in[3];
    const float* al1 = (const float*)d_in[4];
    const float* ar1 = (const float*)d_in[5];
    const float* b1  = (const float*)d_in[6];
    const float* W2  = (const float*)d_in[7];
    const float* al2 = (const float*)d_in[8];
    const float* ar2 = (const float*)d_in[9];
    const float* b2  = (const float*)d_in[10];
    const float* Wf  = (const float*)d_in[11];
    const float* bf  = (const float*)d_in[12];
    float* out = (float*)d_out;

    __half* bufH  = (__half*)d_ws;                       // N*128 fp16 (h)
    __half* bufO  = bufH + (size_t)NN * 128;             // N*128 fp16 (layer1 out)
    float* el     = (float*)(bufO + (size_t)NN * 128);   // N*4
    float* er     = el + NN * 4;                         // N*4
    int* deg      = (int*)(er + NN * 4);                 // N
    int* rowptr   = deg + NN;                            // N+1
    int* csr_src  = rowptr + NN + 1;                     // E
    int* bsum     = csr_src + EE;                        // NBLK
    int* boff     = bsum + NBLK;                         // NBLK

    const int T = 256;
    int gE   = (EE + T - 1) / T;
    int gAgg = (NN + 3) / 4;   // one wave per node, 4 nodes per block

    // CSR build (shared by both layers)
    hipMemsetAsync(deg, 0, NN * sizeof(int), stream);
    degcount_k<<<gE, T, 0, stream>>>(dst, deg);
    blocksum_k<<<NBLK, T, 0, stream>>>(deg, bsum);
    bscan_k<<<1, 128, 0, stream>>>(bsum, boff, rowptr);
    scanout_k<<<NBLK, T, 0, stream>>>(deg, boff, rowptr);
    scatter_rng_k<<<RB, 512, 0, stream>>>(src, dst, rowptr, csr_src);

    // layer 1
    gemm_el_k<0><<<NN / 32, T, 0, stream>>>(x, W1, al1, ar1, bufH, el, er);
    gat_agg_k<0><<<gAgg, T, 0, stream>>>(rowptr, csr_src, el, er, bufH, b1, bufO,
                                         nullptr, nullptr);
    // layer 2 (classifier fused into aggregation epilogue)
    gemm_el_k<1><<<NN / 32, T, 0, stream>>>(bufO, W2, al2, ar2, bufH, el, er);
    gat_agg_k<1><<<gAgg, T, 0, stream>>>(rowptr, csr_src, el, er, bufH, b2, out,
                                         Wf, bf);
}

// Round 10
// 468.430 us; speedup vs baseline: 2.2596x; 2.2596x over previous
//
#include <hip/hip_runtime.h>
#include <hip/hip_fp16.h>

#define NN 100000
#define EE 1600000
#define SCAN_CHUNK 1024
#define NBLK ((NN + SCAN_CHUNK - 1) / SCAN_CHUNK)  // 98
#define NGRP 8                       // dst groups (one per XCD cohort)
#define GR ((NN + NGRP - 1) / NGRP)  // 12500 dst nodes per group
#define NSLICE 32                    // edge slices
#define ES (EE / NSLICE)             // 50000 edges per slice

// ---------- GEMM (Nx128)@(128x128), fp16 out + fused el/er; INHALF: fp16 in ----------
template <int INHALF>
__global__ __launch_bounds__(256) void gemm_el_k(const void* __restrict__ Xv,
                                                 const float* __restrict__ W,
                                                 const float* __restrict__ al,
                                                 const float* __restrict__ ar,
                                                 __half* __restrict__ Hout,
                                                 float* __restrict__ el,
                                                 float* __restrict__ er) {
    __shared__ float Xs[32 * 128];
    __shared__ float Ws[32 * 128];
    int t = threadIdx.x;
    int row0 = blockIdx.x * 32;

    float4* Xs4 = (float4*)Xs;
    if (INHALF) {
        const uint2* Xh = (const uint2*)((const __half*)Xv + (size_t)row0 * 128);
#pragma unroll
        for (int i = 0; i < 4; i++) {
            uint2 u = Xh[i * 256 + t];
            float2 fa = __half22float2(__builtin_bit_cast(__half2, u.x));
            float2 fb = __half22float2(__builtin_bit_cast(__half2, u.y));
            Xs4[i * 256 + t] = make_float4(fa.x, fa.y, fb.x, fb.y);
        }
    } else {
        const float4* X4 = (const float4*)((const float*)Xv + (size_t)row0 * 128);
#pragma unroll
        for (int i = 0; i < 4; i++) Xs4[i * 256 + t] = X4[i * 256 + t];
    }

    int tr = t >> 5, tc = t & 31;
    float acc[4][4] = {};
    for (int kb = 0; kb < 4; kb++) {
        const float4* W4 = (const float4*)(W + kb * 32 * 128);
        float4* Ws4 = (float4*)Ws;
        __syncthreads();
#pragma unroll
        for (int i = 0; i < 4; i++) Ws4[i * 256 + t] = W4[i * 256 + t];
        __syncthreads();
#pragma unroll
        for (int k = 0; k < 32; k += 2) {
            float2 xr[4];
#pragma unroll
            for (int i = 0; i < 4; i++)
                xr[i] = *(const float2*)&Xs[(tr * 4 + i) * 128 + kb * 32 + k];
            float4 w0 = *(const float4*)&Ws[k * 128 + tc * 4];
            float4 w1 = *(const float4*)&Ws[(k + 1) * 128 + tc * 4];
#pragma unroll
            for (int i = 0; i < 4; i++) {
                acc[i][0] += xr[i].x * w0.x + xr[i].y * w1.x;
                acc[i][1] += xr[i].x * w0.y + xr[i].y * w1.y;
                acc[i][2] += xr[i].x * w0.z + xr[i].y * w1.z;
                acc[i][3] += xr[i].x * w0.w + xr[i].y * w1.w;
            }
        }
    }
#pragma unroll
    for (int i = 0; i < 4; i++) {
        __half2 p0 = __floats2half2_rn(acc[i][0], acc[i][1]);
        __half2 p1 = __floats2half2_rn(acc[i][2], acc[i][3]);
        __half2* dstp = (__half2*)&Hout[(size_t)(row0 + tr * 4 + i) * 128 + tc * 4];
        dstp[0] = p0;
        dstp[1] = p1;
    }
    int hd = tc >> 3;
    float4 a_l = *(const float4*)&al[hd * 32 + (tc & 7) * 4];
    float4 a_r = *(const float4*)&ar[hd * 32 + (tc & 7) * 4];
#pragma unroll
    for (int i = 0; i < 4; i++) {
        float pl = acc[i][0] * a_l.x + acc[i][1] * a_l.y + acc[i][2] * a_l.z + acc[i][3] * a_l.w;
        float pr = acc[i][0] * a_r.x + acc[i][1] * a_r.y + acc[i][2] * a_r.z + acc[i][3] * a_r.w;
#pragma unroll
        for (int off = 1; off < 8; off <<= 1) {
            pl += __shfl_xor(pl, off, 64);
            pr += __shfl_xor(pr, off, 64);
        }
        if ((t & 7) == 0) {
            int r = row0 + tr * 4 + i;
            el[r * 4 + hd] = pl;
            er[r * 4 + hd] = pr;
        }
    }
}

// ---------------- CSR build (once per call) ----------------
__global__ void degcount_k(const int* __restrict__ dst, int* __restrict__ deg) {
    int e = blockIdx.x * blockDim.x + threadIdx.x;
    if (e < EE) atomicAdd(&deg[dst[e]], 1);
}

__global__ __launch_bounds__(256) void blocksum_k(const int* __restrict__ deg,
                                                  int* __restrict__ bsum) {
    int b = blockIdx.x, t = threadIdx.x;
    int base = b * SCAN_CHUNK + t * 4;
    int s = 0;
    if (base + 3 < NN) {
        int4 v = *(const int4*)&deg[base];
        s = v.x + v.y + v.z + v.w;
    } else {
        for (int i = base; i < NN; ++i) s += deg[i];
    }
#pragma unroll
    for (int off = 1; off < 64; off <<= 1) s += __shfl_xor(s, off, 64);
    __shared__ int wsum[4];
    if ((t & 63) == 0) wsum[t >> 6] = s;
    __syncthreads();
    if (t == 0) bsum[b] = wsum[0] + wsum[1] + wsum[2] + wsum[3];
}

__global__ __launch_bounds__(128) void bscan_k(const int* __restrict__ bsum,
                                               int* __restrict__ boff,
                                               int* __restrict__ rowptr) {
    __shared__ int sh[128];
    int t = threadIdx.x;
    int v = (t < NBLK) ? bsum[t] : 0;
    sh[t] = v;
    __syncthreads();
    for (int off = 1; off < 128; off <<= 1) {
        int u = (t >= off) ? sh[t - off] : 0;
        __syncthreads();
        sh[t] += u;
        __syncthreads();
    }
    if (t < NBLK) boff[t] = sh[t] - v;
    if (t == 0) rowptr[NN] = EE;
}

__global__ __launch_bounds__(256) void scanout_k(const int* __restrict__ deg,
                                                 const int* __restrict__ boff,
                                                 int* __restrict__ rowptr,
                                                 int* __restrict__ cursor) {
    int b = blockIdx.x, t = threadIdx.x;
    int base = b * SCAN_CHUNK + t * 4;
    int v0 = 0, v1 = 0, v2 = 0, v3 = 0;
    if (base + 3 < NN) {
        int4 v = *(const int4*)&deg[base];
        v0 = v.x; v1 = v.y; v2 = v.z; v3 = v.w;
    } else if (base < NN) {
        v0 = deg[base];
        if (base + 1 < NN) v1 = deg[base + 1];
        if (base + 2 < NN) v2 = deg[base + 2];
    }
    int tot = v0 + v1 + v2 + v3;
    __shared__ int sh[256];
    sh[t] = tot;
    __syncthreads();
    for (int off = 1; off < 256; off <<= 1) {
        int u = (t >= off) ? sh[t - off] : 0;
        __syncthreads();
        sh[t] += u;
        __syncthreads();
    }
    int ex = sh[t] - tot + boff[b];
    if (base + 3 < NN) {
        int4 rv = make_int4(ex, ex + v0, ex + v0 + v1, ex + v0 + v1 + v2);
        *(int4*)&rowptr[base] = rv;
        *(int4*)&cursor[base] = rv;
    } else if (base < NN) {
        rowptr[base] = ex; cursor[base] = ex;
        if (base + 1 < NN) { rowptr[base + 1] = ex + v0; cursor[base + 1] = ex + v0; }
        if (base + 2 < NN) { rowptr[base + 2] = ex + v0 + v1; cursor[base + 2] = ex + v0 + v1; }
    }
}

// XCD-cohort scatter: block bid -> dst group g = bid&7 (same-XCD cohort under
// round-robin dispatch), edge slice bid>>3. All csr_src stores for a dst group
// come from one XCD -> its ~800 KB csr region stays L2-resident, evicts once.
// Full-device parallelism: 256 blocks x 512 threads.
__global__ __launch_bounds__(512) void scatter_xcd_k(const int* __restrict__ src,
                                                     const int* __restrict__ dst,
                                                     int* __restrict__ cursor,
                                                     int* __restrict__ csr_src) {
    int g = blockIdx.x & (NGRP - 1);
    int slice = blockIdx.x >> 3;
    int lo = g * GR;
    int e_beg = slice * ES, e_end = e_beg + ES;
    for (int e0 = e_beg + threadIdx.x * 4; e0 < e_end; e0 += 512 * 4) {
        int4 d4 = *(const int4*)&dst[e0];
        int4 s4 = *(const int4*)&src[e0];
        int dd[4] = {d4.x, d4.y, d4.z, d4.w};
        int ss[4] = {s4.x, s4.y, s4.z, s4.w};
#pragma unroll
        for (int j = 0; j < 4; ++j) {
            unsigned r = (unsigned)(dd[j] - lo);
            if (r < (unsigned)GR) {
                int p = atomicAdd(&cursor[dd[j]], 1);
                csr_src[p] = ss[j];
            }
        }
    }
}

// ---------- fused per-node softmax + aggregation (no-max, masked-32 chunks) ----------
template <int FINAL>
__global__ __launch_bounds__(256) void gat_agg_k(const int* __restrict__ rowptr,
                                                 const int* __restrict__ csr_src,
                                                 const float* __restrict__ el,
                                                 const float* __restrict__ er,
                                                 const __half* __restrict__ h,
                                                 const float* __restrict__ bias,
                                                 void* __restrict__ outv,
                                                 const float* __restrict__ Wf,
                                                 const float* __restrict__ bf) {
    int wave = (blockIdx.x * 256 + threadIdx.x) >> 6;
    if (wave >= NN) return;
    int lane = threadIdx.x & 63;
    int row = rowptr[wave], end = rowptr[wave + 1];
    int hd = lane >> 4, sub = lane & 15;
    float erd = er[wave * 4 + hd];

    float dpart = 0.f, acc0 = 0.f, acc1 = 0.f;
    for (int base = row; base < end; base += 32) {
        int c = end - base;
        int s0 = csr_src[base + (sub < c ? sub : 0)];
        int s1 = csr_src[base + (16 + sub < c ? 16 + sub : 0)];
        __half2 hv[32];
#pragma unroll
        for (int i = 0; i < 16; ++i) {
            int si = __builtin_amdgcn_readlane(s0, i);
            hv[i] = *(const __half2*)(h + (size_t)si * 128 + lane * 2);
        }
#pragma unroll
        for (int i = 0; i < 16; ++i) {
            int si = __builtin_amdgcn_readlane(s1, i);
            hv[16 + i] = *(const __half2*)(h + (size_t)si * 128 + lane * 2);
        }
        float a0 = 0.f, a1 = 0.f;
        if (sub < c) {
            float v = el[s0 * 4 + hd] + erd;
            v = (v >= 0.f) ? v : 0.2f * v;
            a0 = __expf(v);
        }
        if (16 + sub < c) {
            float v = el[s1 * 4 + hd] + erd;
            v = (v >= 0.f) ? v : 0.2f * v;
            a1 = __expf(v);
        }
        dpart += a0 + a1;
#pragma unroll
        for (int i = 0; i < 16; ++i) {
            float ai = __shfl(a0, (hd << 4) | i, 64);
            float2 f = __half22float2(hv[i]);
            acc0 = fmaf(ai, f.x, acc0);
            acc1 = fmaf(ai, f.y, acc1);
        }
#pragma unroll
        for (int i = 0; i < 16; ++i) {
            float ai = __shfl(a1, (hd << 4) | i, 64);
            float2 f = __half22float2(hv[16 + i]);
            acc0 = fmaf(ai, f.x, acc0);
            acc1 = fmaf(ai, f.y, acc1);
        }
    }
    float denom = dpart;
#pragma unroll
    for (int off = 1; off < 16; off <<= 1) denom += __shfl_xor(denom, off, 64);
    float inv = 1.f / fmaxf(denom, 1e-9f);
    float2 bv = *(const float2*)&bias[lane * 2];
    float o0 = acc0 * inv + bv.x;
    float o1 = acc1 * inv + bv.y;

    if (FINAL) {
        float* out = (float*)outv;
        float4 wf = *(const float4*)&Wf[lane * 4];
        float c0 = o0 * wf.x + o1 * wf.z;
        float c1 = o0 * wf.y + o1 * wf.w;
#pragma unroll
        for (int off = 1; off < 64; off <<= 1) {
            c0 += __shfl_xor(c0, off, 64);
            c1 += __shfl_xor(c1, off, 64);
        }
        if (lane == 0) {
            float2 res = make_float2(c0 + bf[0], c1 + bf[1]);
            *(float2*)&out[(size_t)wave * 2] = res;
        }
    } else {
        __half* out = (__half*)outv;
        *(__half2*)&out[(size_t)wave * 128 + lane * 2] = __floats2half2_rn(o0, o1);
    }
}

extern "C" void kernel_launch(void* const* d_in, const int* in_sizes, int n_in,
                              void* d_out, int out_size, void* d_ws, size_t ws_size,
                              hipStream_t stream) {
    const float* x   = (const float*)d_in[0];
    const int*   src = (const int*)d_in[1];
    const int*   dst = (const int*)d_in[2];
    const float* W1  = (const float*)d_in[3];
    const float* al1 = (const float*)d_in[4];
    const float* ar1 = (const float*)d_in[5];
    const float* b1  = (const float*)d_in[6];
    const float* W2  = (const float*)d_in[7];
    const float* al2 = (const float*)d_in[8];
    const float* ar2 = (const float*)d_in[9];
    const float* b2  = (const float*)d_in[10];
    const float* Wf  = (const float*)d_in[11];
    const float* bf  = (const float*)d_in[12];
    float* out = (float*)d_out;

    __half* bufH  = (__half*)d_ws;                       // N*128 fp16 (h)
    __half* bufO  = bufH + (size_t)NN * 128;             // N*128 fp16 (layer1 out)
    float* el     = (float*)(bufO + (size_t)NN * 128);   // N*4
    float* er     = el + NN * 4;                         // N*4
    int* deg      = (int*)(er + NN * 4);                 // N
    int* rowptr   = deg + NN;                            // N+1
    int* cursor   = rowptr + NN + 1;                     // N
    int* csr_src  = cursor + NN;                         // E
    int* bsum     = csr_src + EE;                        // NBLK
    int* boff     = bsum + NBLK;                         // NBLK

    const int T = 256;
    int gE   = (EE + T - 1) / T;
    int gAgg = (NN + 3) / 4;   // one wave per node, 4 nodes per block

    // CSR build (shared by both layers)
    hipMemsetAsync(deg, 0, NN * sizeof(int), stream);
    degcount_k<<<gE, T, 0, stream>>>(dst, deg);
    blocksum_k<<<NBLK, T, 0, stream>>>(deg, bsum);
    bscan_k<<<1, 128, 0, stream>>>(bsum, boff, rowptr);
    scanout_k<<<NBLK, T, 0, stream>>>(deg, boff, rowptr, cursor);
    scatter_xcd_k<<<NGRP * NSLICE, 512, 0, stream>>>(src, dst, cursor, csr_src);

    // layer 1
    gemm_el_k<0><<<NN / 32, T, 0, stream>>>(x, W1, al1, ar1, bufH, el, er);
    gat_agg_k<0><<<gAgg, T, 0, stream>>>(rowptr, csr_src, el, er, bufH, b1, bufO,
                                         nullptr, nullptr);
    // layer 2 (classifier fused into aggregation epilogue)
    gemm_el_k<1><<<NN / 32, T, 0, stream>>>(bufO, W2, al2, ar2, bufH, el, er);
    gat_agg_k<1><<<gAgg, T, 0, stream>>>(rowptr, csr_src, el, er, bufH, b2, out,
                                         Wf, bf);
}

// Round 11
// 361.875 us; speedup vs baseline: 2.9249x; 1.2945x over previous
//
#include <hip/hip_runtime.h>
#include <hip/hip_fp16.h>

#define NN 100000
#define EE 1600000
#define SCAN_CHUNK 1024
#define NBLK ((NN + SCAN_CHUNK - 1) / SCAN_CHUNK)  // 98
#define NGRP 8                       // dst groups (one per XCD cohort)
#define GR ((NN + NGRP - 1) / NGRP)  // 12500 dst nodes per group
#define NSLICE 32                    // edge slices
#define ES (EE / NSLICE)             // 50000 edges per slice

typedef _Float16 f16x8 __attribute__((ext_vector_type(8)));
typedef float f32x4 __attribute__((ext_vector_type(4)));

// ---------- W pre-transpose + fp16 convert: Wt[n][k] = (half)W[k][n] ----------
__global__ __launch_bounds__(256) void wtrans_k(const float* __restrict__ W,
                                                __half* __restrict__ Wt) {
    int t = blockIdx.x * 256 + threadIdx.x;  // 0..16383
    int k = t >> 7, n = t & 127;
    Wt[n * 128 + k] = __float2half(W[k * 128 + n]);
}

// ---------- MFMA GEMM (Nx128)@(128x128), fp16 in/out, fused el/er ----------
// 64 rows/block, 256 threads = 4 waves; wave w computes rows w*16..w*16+15.
// LDS: Xs 64x128 fp16 (16KB) + Ws(=Wt) 128x128 fp16 (32KB), both XOR-swizzled
// at 16B granularity (kb ^= (row&7)<<4) for conflict-free ds_read_b128.
template <int INHALF>
__global__ __launch_bounds__(256) void gemm_el_k(const void* __restrict__ Xv,
                                                 const __half* __restrict__ Wt,
                                                 const float* __restrict__ al,
                                                 const float* __restrict__ ar,
                                                 __half* __restrict__ Hout,
                                                 float* __restrict__ el,
                                                 float* __restrict__ er) {
    __shared__ alignas(16) unsigned short Xs[64 * 128];
    __shared__ alignas(16) unsigned short Ws[128 * 128];
    int t = threadIdx.x;
    int row0 = blockIdx.x * 64;

    // stage Wt -> Ws (2048 x 16B chunks)
    {
        const uint4* g = (const uint4*)Wt;
#pragma unroll
        for (int j = 0; j < 8; ++j) {
            int c = j * 256 + t;
            uint4 v = g[c];
            int n = c >> 4, kb = (c & 15) << 4;
            *(uint4*)((char*)Ws + n * 256 + (kb ^ ((n & 7) << 4))) = v;
        }
    }
    // stage X -> Xs (1024 x 16B fp16 chunks), fp32->fp16 convert if !INHALF
#pragma unroll
    for (int j = 0; j < 4; ++j) {
        int c = j * 256 + t;
        int row = c >> 4, kb = (c & 15) << 4;
        int grow = row0 + row; if (grow >= NN) grow = NN - 1;
        uint4 pk;
        if (INHALF) {
            pk = ((const uint4*)Xv)[(size_t)grow * 16 + (c & 15)];
        } else {
            const float4* xp = (const float4*)Xv + (size_t)grow * 32 + (c & 15) * 2;
            float4 v0 = xp[0], v1 = xp[1];
            __half2 h01 = __floats2half2_rn(v0.x, v0.y);
            __half2 h23 = __floats2half2_rn(v0.z, v0.w);
            __half2 h45 = __floats2half2_rn(v1.x, v1.y);
            __half2 h67 = __floats2half2_rn(v1.z, v1.w);
            pk = make_uint4(__builtin_bit_cast(unsigned, h01),
                            __builtin_bit_cast(unsigned, h23),
                            __builtin_bit_cast(unsigned, h45),
                            __builtin_bit_cast(unsigned, h67));
        }
        *(uint4*)((char*)Xs + row * 256 + (kb ^ ((row & 7) << 4))) = pk;
    }
    __syncthreads();

    int w = t >> 6, lane = t & 63;
    int lr = lane & 15, lg = lane >> 4;
    int arow = w * 16 + lr;

    f32x4 acc[8] = {};
#pragma unroll
    for (int ks = 0; ks < 4; ++ks) {
        int kb = ks * 64 + lg * 16;
        f16x8 a = *(const f16x8*)((char*)Xs + arow * 256 + (kb ^ ((arow & 7) << 4)));
#pragma unroll
        for (int ct = 0; ct < 8; ++ct) {
            int brow = ct * 16 + lr;
            f16x8 b = *(const f16x8*)((char*)Ws + brow * 256 + (kb ^ ((brow & 7) << 4)));
            acc[ct] = __builtin_amdgcn_mfma_f32_16x16x32_f16(a, b, acc[ct], 0, 0, 0);
        }
    }

    // ---- store h (fp16) : lane holds C[lg*4+r][ct*16+lr] ----
#pragma unroll
    for (int r = 0; r < 4; ++r) {
        int grow = row0 + w * 16 + lg * 4 + r;
        if (grow < NN) {
            __half* hp = Hout + (size_t)grow * 128 + lr;
#pragma unroll
            for (int ct = 0; ct < 8; ++ct)
                hp[ct * 16] = __float2half(acc[ct][r]);
        }
    }
    // ---- fused el/er from fp32 accumulators ----
    float alv[8], arv[8];
#pragma unroll
    for (int ct = 0; ct < 8; ++ct) {
        alv[ct] = al[ct * 16 + lr];
        arv[ct] = ar[ct * 16 + lr];
    }
#pragma unroll
    for (int r = 0; r < 4; ++r) {
        int grow = row0 + w * 16 + lg * 4 + r;
#pragma unroll
        for (int hd = 0; hd < 4; ++hd) {
            float pl = acc[2 * hd][r] * alv[2 * hd] + acc[2 * hd + 1][r] * alv[2 * hd + 1];
            float pr = acc[2 * hd][r] * arv[2 * hd] + acc[2 * hd + 1][r] * arv[2 * hd + 1];
#pragma unroll
            for (int off = 1; off < 16; off <<= 1) {
                pl += __shfl_xor(pl, off, 64);
                pr += __shfl_xor(pr, off, 64);
            }
            if (lr == 0 && grow < NN) {
                el[grow * 4 + hd] = pl;
                er[grow * 4 + hd] = pr;
            }
        }
    }
}

// ---------------- CSR build (once per call) ----------------
__global__ void degcount_k(const int* __restrict__ dst, int* __restrict__ deg) {
    int e = blockIdx.x * blockDim.x + threadIdx.x;
    if (e < EE) atomicAdd(&deg[dst[e]], 1);
}

__global__ __launch_bounds__(256) void blocksum_k(const int* __restrict__ deg,
                                                  int* __restrict__ bsum) {
    int b = blockIdx.x, t = threadIdx.x;
    int base = b * SCAN_CHUNK + t * 4;
    int s = 0;
    if (base + 3 < NN) {
        int4 v = *(const int4*)&deg[base];
        s = v.x + v.y + v.z + v.w;
    } else {
        for (int i = base; i < NN; ++i) s += deg[i];
    }
#pragma unroll
    for (int off = 1; off < 64; off <<= 1) s += __shfl_xor(s, off, 64);
    __shared__ int wsum[4];
    if ((t & 63) == 0) wsum[t >> 6] = s;
    __syncthreads();
    if (t == 0) bsum[b] = wsum[0] + wsum[1] + wsum[2] + wsum[3];
}

__global__ __launch_bounds__(128) void bscan_k(const int* __restrict__ bsum,
                                               int* __restrict__ boff,
                                               int* __restrict__ rowptr) {
    __shared__ int sh[128];
    int t = threadIdx.x;
    int v = (t < NBLK) ? bsum[t] : 0;
    sh[t] = v;
    __syncthreads();
    for (int off = 1; off < 128; off <<= 1) {
        int u = (t >= off) ? sh[t - off] : 0;
        __syncthreads();
        sh[t] += u;
        __syncthreads();
    }
    if (t < NBLK) boff[t] = sh[t] - v;
    if (t == 0) rowptr[NN] = EE;
}

__global__ __launch_bounds__(256) void scanout_k(const int* __restrict__ deg,
                                                 const int* __restrict__ boff,
                                                 int* __restrict__ rowptr,
                                                 int* __restrict__ cursor) {
    int b = blockIdx.x, t = threadIdx.x;
    int base = b * SCAN_CHUNK + t * 4;
    int v0 = 0, v1 = 0, v2 = 0, v3 = 0;
    if (base + 3 < NN) {
        int4 v = *(const int4*)&deg[base];
        v0 = v.x; v1 = v.y; v2 = v.z; v3 = v.w;
    } else if (base < NN) {
        v0 = deg[base];
        if (base + 1 < NN) v1 = deg[base + 1];
        if (base + 2 < NN) v2 = deg[base + 2];
    }
    int tot = v0 + v1 + v2 + v3;
    __shared__ int sh[256];
    sh[t] = tot;
    __syncthreads();
    for (int off = 1; off < 256; off <<= 1) {
        int u = (t >= off) ? sh[t - off] : 0;
        __syncthreads();
        sh[t] += u;
        __syncthreads();
    }
    int ex = sh[t] - tot + boff[b];
    if (base + 3 < NN) {
        int4 rv = make_int4(ex, ex + v0, ex + v0 + v1, ex + v0 + v1 + v2);
        *(int4*)&rowptr[base] = rv;
        *(int4*)&cursor[base] = rv;
    } else if (base < NN) {
        rowptr[base] = ex; cursor[base] = ex;
        if (base + 1 < NN) { rowptr[base + 1] = ex + v0; cursor[base + 1] = ex + v0; }
        if (base + 2 < NN) { rowptr[base + 2] = ex + v0 + v1; cursor[base + 2] = ex + v0 + v1; }
    }
}

// XCD-cohort scatter: block bid -> dst group g = bid&7, edge slice bid>>3.
__global__ __launch_bounds__(512) void scatter_xcd_k(const int* __restrict__ src,
                                                     const int* __restrict__ dst,
                                                     int* __restrict__ cursor,
                                                     int* __restrict__ csr_src) {
    int g = blockIdx.x & (NGRP - 1);
    int slice = blockIdx.x >> 3;
    int lo = g * GR;
    int e_beg = slice * ES, e_end = e_beg + ES;
    for (int e0 = e_beg + threadIdx.x * 4; e0 < e_end; e0 += 512 * 4) {
        int4 d4 = *(const int4*)&dst[e0];
        int4 s4 = *(const int4*)&src[e0];
        int dd[4] = {d4.x, d4.y, d4.z, d4.w};
        int ss[4] = {s4.x, s4.y, s4.z, s4.w};
#pragma unroll
        for (int j = 0; j < 4; ++j) {
            unsigned r = (unsigned)(dd[j] - lo);
            if (r < (unsigned)GR) {
                int p = atomicAdd(&cursor[dd[j]], 1);
                csr_src[p] = ss[j];
            }
        }
    }
}

// ---------- fused per-node softmax + aggregation (no-max, masked-32 chunks) ----------
template <int FINAL>
__global__ __launch_bounds__(256) void gat_agg_k(const int* __restrict__ rowptr,
                                                 const int* __restrict__ csr_src,
                                                 const float* __restrict__ el,
                                                 const float* __restrict__ er,
                                                 const __half* __restrict__ h,
                                                 const float* __restrict__ bias,
                                                 void* __restrict__ outv,
                                                 const float* __restrict__ Wf,
                                                 const float* __restrict__ bf) {
    int wave = (blockIdx.x * 256 + threadIdx.x) >> 6;
    if (wave >= NN) return;
    int lane = threadIdx.x & 63;
    int row = rowptr[wave], end = rowptr[wave + 1];
    int hd = lane >> 4, sub = lane & 15;
    float erd = er[wave * 4 + hd];

    float dpart = 0.f, acc0 = 0.f, acc1 = 0.f;
    for (int base = row; base < end; base += 32) {
        int c = end - base;
        int s0 = csr_src[base + (sub < c ? sub : 0)];
        int s1 = csr_src[base + (16 + sub < c ? 16 + sub : 0)];
        __half2 hv[32];
#pragma unroll
        for (int i = 0; i < 16; ++i) {
            int si = __builtin_amdgcn_readlane(s0, i);
            hv[i] = *(const __half2*)(h + (size_t)si * 128 + lane * 2);
        }
#pragma unroll
        for (int i = 0; i < 16; ++i) {
            int si = __builtin_amdgcn_readlane(s1, i);
            hv[16 + i] = *(const __half2*)(h + (size_t)si * 128 + lane * 2);
        }
        float a0 = 0.f, a1 = 0.f;
        if (sub < c) {
            float v = el[s0 * 4 + hd] + erd;
            v = (v >= 0.f) ? v : 0.2f * v;
            a0 = __expf(v);
        }
        if (16 + sub < c) {
            float v = el[s1 * 4 + hd] + erd;
            v = (v >= 0.f) ? v : 0.2f * v;
            a1 = __expf(v);
        }
        dpart += a0 + a1;
#pragma unroll
        for (int i = 0; i < 16; ++i) {
            float ai = __shfl(a0, (hd << 4) | i, 64);
            float2 f = __half22float2(hv[i]);
            acc0 = fmaf(ai, f.x, acc0);
            acc1 = fmaf(ai, f.y, acc1);
        }
#pragma unroll
        for (int i = 0; i < 16; ++i) {
            float ai = __shfl(a1, (hd << 4) | i, 64);
            float2 f = __half22float2(hv[16 + i]);
            acc0 = fmaf(ai, f.x, acc0);
            acc1 = fmaf(ai, f.y, acc1);
        }
    }
    float denom = dpart;
#pragma unroll
    for (int off = 1; off < 16; off <<= 1) denom += __shfl_xor(denom, off, 64);
    float inv = 1.f / fmaxf(denom, 1e-9f);
    float2 bv = *(const float2*)&bias[lane * 2];
    float o0 = acc0 * inv + bv.x;
    float o1 = acc1 * inv + bv.y;

    if (FINAL) {
        float* out = (float*)outv;
        float4 wf = *(const float4*)&Wf[lane * 4];
        float c0 = o0 * wf.x + o1 * wf.z;
        float c1 = o0 * wf.y + o1 * wf.w;
#pragma unroll
        for (int off = 1; off < 64; off <<= 1) {
            c0 += __shfl_xor(c0, off, 64);
            c1 += __shfl_xor(c1, off, 64);
        }
        if (lane == 0) {
            float2 res = make_float2(c0 + bf[0], c1 + bf[1]);
            *(float2*)&out[(size_t)wave * 2] = res;
        }
    } else {
        __half* out = (__half*)outv;
        *(__half2*)&out[(size_t)wave * 128 + lane * 2] = __floats2half2_rn(o0, o1);
    }
}

extern "C" void kernel_launch(void* const* d_in, const int* in_sizes, int n_in,
                              void* d_out, int out_size, void* d_ws, size_t ws_size,
                              hipStream_t stream) {
    const float* x   = (const float*)d_in[0];
    const int*   src = (const int*)d_in[1];
    const int*   dst = (const int*)d_in[2];
    const float* W1  = (const float*)d_in[3];
    const float* al1 = (const float*)d_in[4];
    const float* ar1 = (const float*)d_in[5];
    const float* b1  = (const float*)d_in[6];
    const float* W2  = (const float*)d_in[7];
    const float* al2 = (const float*)d_in[8];
    const float* ar2 = (const float*)d_in[9];
    const float* b2  = (const float*)d_in[10];
    const float* Wf  = (const float*)d_in[11];
    const float* bf  = (const float*)d_in[12];
    float* out = (float*)d_out;

    __half* bufH  = (__half*)d_ws;                       // N*128 fp16 (h)
    __half* bufO  = bufH + (size_t)NN * 128;             // N*128 fp16 (layer1 out)
    float* el     = (float*)(bufO + (size_t)NN * 128);   // N*4
    float* er     = el + NN * 4;                         // N*4
    int* deg      = (int*)(er + NN * 4);                 // N
    int* rowptr   = deg + NN;                            // N+1
    int* cursor   = rowptr + NN + 1;                     // N
    int* csr_src  = cursor + NN;                         // E
    int* bsum     = csr_src + EE;                        // NBLK
    int* boff     = bsum + NBLK;                         // NBLK
    __half* Wt1   = (__half*)(boff + NBLK);              // 128*128 fp16
    __half* Wt2   = Wt1 + 128 * 128;                     // 128*128 fp16

    const int T = 256;
    int gE    = (EE + T - 1) / T;
    int gAgg  = (NN + 3) / 4;      // one wave per node, 4 nodes per block
    int gGemm = (NN + 63) / 64;    // 64 rows per block

    // W pre-transpose/convert + CSR build (independent of GEMM inputs)
    wtrans_k<<<64, T, 0, stream>>>(W1, Wt1);
    wtrans_k<<<64, T, 0, stream>>>(W2, Wt2);
    hipMemsetAsync(deg, 0, NN * sizeof(int), stream);
    degcount_k<<<gE, T, 0, stream>>>(dst, deg);
    blocksum_k<<<NBLK, T, 0, stream>>>(deg, bsum);
    bscan_k<<<1, 128, 0, stream>>>(bsum, boff, rowptr);
    scanout_k<<<NBLK, T, 0, stream>>>(deg, boff, rowptr, cursor);
    scatter_xcd_k<<<NGRP * NSLICE, 512, 0, stream>>>(src, dst, cursor, csr_src);

    // layer 1
    gemm_el_k<0><<<gGemm, T, 0, stream>>>(x, Wt1, al1, ar1, bufH, el, er);
    gat_agg_k<0><<<gAgg, T, 0, stream>>>(rowptr, csr_src, el, er, bufH, b1, bufO,
                                         nullptr, nullptr);
    // layer 2 (classifier fused into aggregation epilogue)
    gemm_el_k<1><<<gGemm, T, 0, stream>>>(bufO, Wt2, al2, ar2, bufH, el, er);
    gat_agg_k<1><<<gAgg, T, 0, stream>>>(rowptr, csr_src, el, er, bufH, b2, out,
                                         Wf, bf);
}

// Round 13
// 340.218 us; speedup vs baseline: 3.1111x; 1.0637x over previous
//
#include <hip/hip_runtime.h>
#include <hip/hip_fp16.h>

#define NN 100000
#define EE 1600000
#define SCAN_CHUNK 1024
#define NBLK ((NN + SCAN_CHUNK - 1) / SCAN_CHUNK)  // 98
#define NGRP 8                       // dst groups (one per XCD cohort)
#define GR ((NN + NGRP - 1) / NGRP)  // 12500 dst nodes per group
#define NSLICE 32                    // edge slices
#define ES (EE / NSLICE)             // 50000 edges per slice

typedef _Float16 f16x8 __attribute__((ext_vector_type(8)));
typedef float f32x4 __attribute__((ext_vector_type(4)));

// ---------- W pre-transpose + fp16 convert: Wt[n][k] = (half)W[k][n] ----------
__global__ __launch_bounds__(256) void wtrans_k(const float* __restrict__ W,
                                                __half* __restrict__ Wt) {
    int t = blockIdx.x * 256 + threadIdx.x;  // 0..16383
    int k = t >> 7, n = t & 127;
    Wt[n * 128 + k] = __float2half(W[k * 128 + n]);
}

// ---------- MFMA GEMM (Nx128)@(128x128), fp16 in/out, fused el/er ----------
template <int INHALF>
__global__ __launch_bounds__(256) void gemm_el_k(const void* __restrict__ Xv,
                                                 const __half* __restrict__ Wt,
                                                 const float* __restrict__ al,
                                                 const float* __restrict__ ar,
                                                 __half* __restrict__ Hout,
                                                 float* __restrict__ el,
                                                 float* __restrict__ er) {
    __shared__ alignas(16) unsigned short Xs[64 * 128];
    __shared__ alignas(16) unsigned short Ws[128 * 128];
    int t = threadIdx.x;
    int row0 = blockIdx.x * 64;

    // stage Wt -> Ws (2048 x 16B chunks)
    {
        const uint4* g = (const uint4*)Wt;
#pragma unroll
        for (int j = 0; j < 8; ++j) {
            int c = j * 256 + t;
            uint4 v = g[c];
            int n = c >> 4, kb = (c & 15) << 4;
            *(uint4*)((char*)Ws + n * 256 + (kb ^ ((n & 7) << 4))) = v;
        }
    }
    // stage X -> Xs (1024 x 16B fp16 chunks), fp32->fp16 convert if !INHALF
#pragma unroll
    for (int j = 0; j < 4; ++j) {
        int c = j * 256 + t;
        int row = c >> 4, kb = (c & 15) << 4;
        int grow = row0 + row; if (grow >= NN) grow = NN - 1;
        uint4 pk;
        if (INHALF) {
            pk = ((const uint4*)Xv)[(size_t)grow * 16 + (c & 15)];
        } else {
            const float4* xp = (const float4*)Xv + (size_t)grow * 32 + (c & 15) * 2;
            float4 v0 = xp[0], v1 = xp[1];
            __half2 h01 = __floats2half2_rn(v0.x, v0.y);
            __half2 h23 = __floats2half2_rn(v0.z, v0.w);
            __half2 h45 = __floats2half2_rn(v1.x, v1.y);
            __half2 h67 = __floats2half2_rn(v1.z, v1.w);
            pk = make_uint4(__builtin_bit_cast(unsigned, h01),
                            __builtin_bit_cast(unsigned, h23),
                            __builtin_bit_cast(unsigned, h45),
                            __builtin_bit_cast(unsigned, h67));
        }
        *(uint4*)((char*)Xs + row * 256 + (kb ^ ((row & 7) << 4))) = pk;
    }
    __syncthreads();

    int w = t >> 6, lane = t & 63;
    int lr = lane & 15, lg = lane >> 4;
    int arow = w * 16 + lr;

    f32x4 acc[8] = {};
#pragma unroll
    for (int ks = 0; ks < 4; ++ks) {
        int kb = ks * 64 + lg * 16;
        f16x8 a = *(const f16x8*)((char*)Xs + arow * 256 + (kb ^ ((arow & 7) << 4)));
#pragma unroll
        for (int ct = 0; ct < 8; ++ct) {
            int brow = ct * 16 + lr;
            f16x8 b = *(const f16x8*)((char*)Ws + brow * 256 + (kb ^ ((brow & 7) << 4)));
            acc[ct] = __builtin_amdgcn_mfma_f32_16x16x32_f16(a, b, acc[ct], 0, 0, 0);
        }
    }

    // ---- store h (fp16) : lane holds C[lg*4+r][ct*16+lr] ----
#pragma unroll
    for (int r = 0; r < 4; ++r) {
        int grow = row0 + w * 16 + lg * 4 + r;
        if (grow < NN) {
            __half* hp = Hout + (size_t)grow * 128 + lr;
#pragma unroll
            for (int ct = 0; ct < 8; ++ct)
                hp[ct * 16] = __float2half(acc[ct][r]);
        }
    }
    // ---- fused el/er from fp32 accumulators ----
    float alv[8], arv[8];
#pragma unroll
    for (int ct = 0; ct < 8; ++ct) {
        alv[ct] = al[ct * 16 + lr];
        arv[ct] = ar[ct * 16 + lr];
    }
#pragma unroll
    for (int r = 0; r < 4; ++r) {
        int grow = row0 + w * 16 + lg * 4 + r;
#pragma unroll
        for (int hd = 0; hd < 4; ++hd) {
            float pl = acc[2 * hd][r] * alv[2 * hd] + acc[2 * hd + 1][r] * alv[2 * hd + 1];
            float pr = acc[2 * hd][r] * arv[2 * hd] + acc[2 * hd + 1][r] * arv[2 * hd + 1];
#pragma unroll
            for (int off = 1; off < 16; off <<= 1) {
                pl += __shfl_xor(pl, off, 64);
                pr += __shfl_xor(pr, off, 64);
            }
            if (lr == 0 && grow < NN) {
                el[grow * 4 + hd] = pl;
                er[grow * 4 + hd] = pr;
            }
        }
    }
}

// ---------------- CSR build (once per call) ----------------
__global__ void degcount_k(const int* __restrict__ dst, int* __restrict__ deg) {
    int e = blockIdx.x * blockDim.x + threadIdx.x;
    if (e < EE) atomicAdd(&deg[dst[e]], 1);
}

__global__ __launch_bounds__(256) void blocksum_k(const int* __restrict__ deg,
                                                  int* __restrict__ bsum) {
    int b = blockIdx.x, t = threadIdx.x;
    int base = b * SCAN_CHUNK + t * 4;
    int s = 0;
    if (base + 3 < NN) {
        int4 v = *(const int4*)&deg[base];
        s = v.x + v.y + v.z + v.w;
    } else {
        for (int i = base; i < NN; ++i) s += deg[i];
    }
#pragma unroll
    for (int off = 1; off < 64; off <<= 1) s += __shfl_xor(s, off, 64);
    __shared__ int wsum[4];
    if ((t & 63) == 0) wsum[t >> 6] = s;
    __syncthreads();
    if (t == 0) bsum[b] = wsum[0] + wsum[1] + wsum[2] + wsum[3];
}

__global__ __launch_bounds__(128) void bscan_k(const int* __restrict__ bsum,
                                               int* __restrict__ boff,
                                               int* __restrict__ rowptr) {
    __shared__ int sh[128];
    int t = threadIdx.x;
    int v = (t < NBLK) ? bsum[t] : 0;
    sh[t] = v;
    __syncthreads();
    for (int off = 1; off < 128; off <<= 1) {
        int u = (t >= off) ? sh[t - off] : 0;
        __syncthreads();
        sh[t] += u;
        __syncthreads();
    }
    if (t < NBLK) boff[t] = sh[t] - v;
    if (t == 0) rowptr[NN] = EE;
}

__global__ __launch_bounds__(256) void scanout_k(const int* __restrict__ deg,
                                                 const int* __restrict__ boff,
                                                 int* __restrict__ rowptr,
                                                 int* __restrict__ cursor) {
    int b = blockIdx.x, t = threadIdx.x;
    int base = b * SCAN_CHUNK + t * 4;
    int v0 = 0, v1 = 0, v2 = 0, v3 = 0;
    if (base + 3 < NN) {
        int4 v = *(const int4*)&deg[base];
        v0 = v.x; v1 = v.y; v2 = v.z; v3 = v.w;
    } else if (base < NN) {
        v0 = deg[base];
        if (base + 1 < NN) v1 = deg[base + 1];
        if (base + 2 < NN) v2 = deg[base + 2];
    }
    int tot = v0 + v1 + v2 + v3;
    __shared__ int sh[256];
    sh[t] = tot;
    __syncthreads();
    for (int off = 1; off < 256; off <<= 1) {
        int u = (t >= off) ? sh[t - off] : 0;
        __syncthreads();
        sh[t] += u;
        __syncthreads();
    }
    int ex = sh[t] - tot + boff[b];
    if (base + 3 < NN) {
        int4 rv = make_int4(ex, ex + v0, ex + v0 + v1, ex + v0 + v1 + v2);
        *(int4*)&rowptr[base] = rv;
        *(int4*)&cursor[base] = rv;
    } else if (base < NN) {
        rowptr[base] = ex; cursor[base] = ex;
        if (base + 1 < NN) { rowptr[base + 1] = ex + v0; cursor[base + 1] = ex + v0; }
        if (base + 2 < NN) { rowptr[base + 2] = ex + v0 + v1; cursor[base + 2] = ex + v0 + v1; }
    }
}

// XCD-cohort scatter: block bid -> dst group g = bid&7, edge slice bid>>3.
__global__ __launch_bounds__(512) void scatter_xcd_k(const int* __restrict__ src,
                                                     const int* __restrict__ dst,
                                                     int* __restrict__ cursor,
                                                     int* __restrict__ csr_src) {
    int g = blockIdx.x & (NGRP - 1);
    int slice = blockIdx.x >> 3;
    int lo = g * GR;
    int e_beg = slice * ES, e_end = e_beg + ES;
    for (int e0 = e_beg + threadIdx.x * 4; e0 < e_end; e0 += 512 * 4) {
        int4 d4 = *(const int4*)&dst[e0];
        int4 s4 = *(const int4*)&src[e0];
        int dd[4] = {d4.x, d4.y, d4.z, d4.w};
        int ss[4] = {s4.x, s4.y, s4.z, s4.w};
#pragma unroll
        for (int j = 0; j < 4; ++j) {
            unsigned r = (unsigned)(dd[j] - lo);
            if (r < (unsigned)GR) {
                int p = atomicAdd(&cursor[dd[j]], 1);
                csr_src[p] = ss[j];
            }
        }
    }
}

// ---------- fused per-node softmax + aggregation ----------
// ONE WAVE PER WORKGROUP (64 thr). lane = hd*16 + sub. Uniform branch:
// deg<=16 half-chunk. Alpha broadcast within 16-group via static ds_swizzle
// pattern (lane&16)|i — literal constants only (frontend requirement), so the
// 16 steps are macro-expanded.
#define BC16(x, I) __uint_as_float(__builtin_amdgcn_ds_swizzle( \
    __float_as_uint(x), ((I) << 5) | 0x10))

#define AGG_STEP(av, hvp, I)                      \
    {                                             \
        float ai = BC16(av, I);                   \
        float2 f = __half22float2((hvp)[I]);      \
        acc0 = fmaf(ai, f.x, acc0);               \
        acc1 = fmaf(ai, f.y, acc1);               \
    }

#define AGG16(av, hvp)                                                       \
    AGG_STEP(av, hvp, 0)  AGG_STEP(av, hvp, 1)  AGG_STEP(av, hvp, 2)         \
    AGG_STEP(av, hvp, 3)  AGG_STEP(av, hvp, 4)  AGG_STEP(av, hvp, 5)         \
    AGG_STEP(av, hvp, 6)  AGG_STEP(av, hvp, 7)  AGG_STEP(av, hvp, 8)         \
    AGG_STEP(av, hvp, 9)  AGG_STEP(av, hvp, 10) AGG_STEP(av, hvp, 11)        \
    AGG_STEP(av, hvp, 12) AGG_STEP(av, hvp, 13) AGG_STEP(av, hvp, 14)        \
    AGG_STEP(av, hvp, 15)

template <int FINAL>
__global__ __launch_bounds__(64) void gat_agg_k(const int* __restrict__ rowptr,
                                                const int* __restrict__ csr_src,
                                                const float* __restrict__ el,
                                                const float* __restrict__ er,
                                                const __half* __restrict__ h,
                                                const float* __restrict__ bias,
                                                void* __restrict__ outv,
                                                const float* __restrict__ Wf,
                                                const float* __restrict__ bf) {
    int wave = blockIdx.x;
    int lane = threadIdx.x;
    int row = rowptr[wave], end = rowptr[wave + 1];
    int hd = lane >> 4, sub = lane & 15;
    float erd = er[wave * 4 + hd];
    const __half2* hbase = (const __half2*)h + lane;  // + si*64 per gather

    float dpart = 0.f, acc0 = 0.f, acc1 = 0.f;
    for (int base = row; base < end; base += 32) {
        int c = end - base;
        int s0 = csr_src[base + (sub < c ? sub : 0)];
        float a0 = 0.f;
        {
            float v = el[s0 * 4 + hd] + erd;
            v = (v >= 0.f) ? v : 0.2f * v;
            if (sub < c) a0 = __expf(v);
        }
        if (c > 16) {
            int i1 = 16 + sub;
            int s1 = csr_src[base + (i1 < c ? i1 : 0)];
            float a1 = 0.f;
            {
                float v = el[s1 * 4 + hd] + erd;
                v = (v >= 0.f) ? v : 0.2f * v;
                if (i1 < c) a1 = __expf(v);
            }
            dpart += a0 + a1;
            __half2 hv[32];
#pragma unroll
            for (int i = 0; i < 16; ++i) {
                int si = __builtin_amdgcn_readlane(s0, i);
                hv[i] = hbase[si * 64];
            }
#pragma unroll
            for (int i = 0; i < 16; ++i) {
                int si = __builtin_amdgcn_readlane(s1, i);
                hv[16 + i] = hbase[si * 64];
            }
            AGG16(a0, hv)
            AGG16(a1, (hv + 16))
        } else {
            dpart += a0;
            __half2 hv[16];
#pragma unroll
            for (int i = 0; i < 16; ++i) {
                int si = __builtin_amdgcn_readlane(s0, i);
                hv[i] = hbase[si * 64];
            }
            AGG16(a0, hv)
        }
    }
    float denom = dpart;
#pragma unroll
    for (int off = 1; off < 16; off <<= 1) denom += __shfl_xor(denom, off, 64);
    float inv = 1.f / fmaxf(denom, 1e-9f);
    float2 bv = *(const float2*)&bias[lane * 2];
    float o0 = acc0 * inv + bv.x;
    float o1 = acc1 * inv + bv.y;

    if (FINAL) {
        float* out = (float*)outv;
        float4 wf = *(const float4*)&Wf[lane * 4];
        float c0 = o0 * wf.x + o1 * wf.z;
        float c1 = o0 * wf.y + o1 * wf.w;
#pragma unroll
        for (int off = 1; off < 64; off <<= 1) {
            c0 += __shfl_xor(c0, off, 64);
            c1 += __shfl_xor(c1, off, 64);
        }
        if (lane == 0) {
            float2 res = make_float2(c0 + bf[0], c1 + bf[1]);
            *(float2*)&out[(size_t)wave * 2] = res;
        }
    } else {
        __half* out = (__half*)outv;
        *(__half2*)&out[(size_t)wave * 128 + lane * 2] = __floats2half2_rn(o0, o1);
    }
}

extern "C" void kernel_launch(void* const* d_in, const int* in_sizes, int n_in,
                              void* d_out, int out_size, void* d_ws, size_t ws_size,
                              hipStream_t stream) {
    const float* x   = (const float*)d_in[0];
    const int*   src = (const int*)d_in[1];
    const int*   dst = (const int*)d_in[2];
    const float* W1  = (const float*)d_in[3];
    const float* al1 = (const float*)d_in[4];
    const float* ar1 = (const float*)d_in[5];
    const float* b1  = (const float*)d_in[6];
    const float* W2  = (const float*)d_in[7];
    const float* al2 = (const float*)d_in[8];
    const float* ar2 = (const float*)d_in[9];
    const float* b2  = (const float*)d_in[10];
    const float* Wf  = (const float*)d_in[11];
    const float* bf  = (const float*)d_in[12];
    float* out = (float*)d_out;

    __half* bufH  = (__half*)d_ws;                       // N*128 fp16 (h)
    __half* bufO  = bufH + (size_t)NN * 128;             // N*128 fp16 (layer1 out)
    float* el     = (float*)(bufO + (size_t)NN * 128);   // N*4
    float* er     = el + NN * 4;                         // N*4
    int* deg      = (int*)(er + NN * 4);                 // N
    int* rowptr   = deg + NN;                            // N+1
    int* cursor   = rowptr + NN + 1;                     // N
    int* csr_src  = cursor + NN;                         // E
    int* bsum     = csr_src + EE;                        // NBLK
    int* boff     = bsum + NBLK;                         // NBLK
    __half* Wt1   = (__half*)(boff + NBLK);              // 128*128 fp16
    __half* Wt2   = Wt1 + 128 * 128;                     // 128*128 fp16

    const int T = 256;
    int gE    = (EE + T - 1) / T;
    int gGemm = (NN + 63) / 64;    // 64 rows per block

    // W pre-transpose/convert + CSR build (independent of GEMM inputs)
    wtrans_k<<<64, T, 0, stream>>>(W1, Wt1);
    wtrans_k<<<64, T, 0, stream>>>(W2, Wt2);
    (void)hipMemsetAsync(deg, 0, NN * sizeof(int), stream);
    degcount_k<<<gE, T, 0, stream>>>(dst, deg);
    blocksum_k<<<NBLK, T, 0, stream>>>(deg, bsum);
    bscan_k<<<1, 128, 0, stream>>>(bsum, boff, rowptr);
    scanout_k<<<NBLK, T, 0, stream>>>(deg, boff, rowptr, cursor);
    scatter_xcd_k<<<NGRP * NSLICE, 512, 0, stream>>>(src, dst, cursor, csr_src);

    // layer 1
    gemm_el_k<0><<<gGemm, T, 0, stream>>>(x, Wt1, al1, ar1, bufH, el, er);
    gat_agg_k<0><<<NN, 64, 0, stream>>>(rowptr, csr_src, el, er, bufH, b1, bufO,
                                        nullptr, nullptr);
    // layer 2 (classifier fused into aggregation epilogue)
    gemm_el_k<1><<<gGemm, T, 0, stream>>>(bufO, Wt2, al2, ar2, bufH, el, er);
    gat_agg_k<1><<<NN, 64, 0, stream>>>(rowptr, csr_src, el, er, bufH, b2, out,
                                        Wf, bf);
}